// Round 17
// baseline (229.830 us; speedup 1.0000x reference)
//
#include <hip/hip_runtime.h>
#include <hip/hip_bf16.h>
#include <hip/hip_cooperative_groups.h>

// GraphConv layer, R17.
//   g = h@e_w1 (bf16 + fp8 shadow).  T[n] = sum_edges relu(g[n]+eb1 - g8[col]).
//   out = relu(h@A + T@(e_w2@B) + deg*(e_b2@B) + n_b1)@n_w2 + n_b2.
// R17: ONE cooperative kernel (512 blocks x 256 thr, 72KB LDS, 2/CU), phases split by
//      grid.sync(): P0 prep -> P1 {g-tiles (W1 staged once/block) + scatter in-phase}
//      -> P2 agg (FULL 64KB W1 resident; no restage barriers). Kills 3 launch gaps +
//      kernel tails. Falls back to R16 4-kernel path if coop launch fails.

namespace cg = cooperative_groups;

typedef __attribute__((ext_vector_type(4))) float f32x4;
typedef __attribute__((ext_vector_type(2))) float f32x2;
typedef __attribute__((ext_vector_type(8))) __bf16 bf16x8;
typedef __attribute__((ext_vector_type(4))) short s16x4;
typedef __attribute__((ext_vector_type(8))) unsigned short u16x8;

#define SLOT_CAP 64

__device__ __forceinline__ short f2bf(float f) {
  unsigned x = __float_as_uint(f);
  x = (x + 0x7fffu + ((x >> 16) & 1u)) >> 16;
  return (short)x;
}
__device__ __forceinline__ float bf2f(unsigned short u) {
  return __uint_as_float(((unsigned)u) << 16);
}
// XOR swizzle on byte bits 4..6 within a row (G4 / m214 r268)
__device__ __forceinline__ int swzB(int row, int colByte, int strideB) {
  return row * strideB + (colByte ^ ((row & 7) << 4));
}

// decode+accumulate one edge's 16 fp8 dims into tac (masked)
__device__ __forceinline__ void acc16fp8(float* tac, const float* gnb, int4 v, float m) {
  int w[4] = {v.x, v.y, v.z, v.w};
#pragma unroll
  for (int q = 0; q < 4; ++q) {
    f32x2 lo = __builtin_amdgcn_cvt_pk_f32_fp8(w[q], false);
    f32x2 hi = __builtin_amdgcn_cvt_pk_f32_fp8(w[q], true);
    float d0 = gnb[q * 4 + 0] - lo.x;
    float d1 = gnb[q * 4 + 1] - lo.y;
    float d2 = gnb[q * 4 + 2] - hi.x;
    float d3 = gnb[q * 4 + 3] - hi.y;
    tac[q * 4 + 0] += m * (d0 > 0.f ? d0 : 0.f);
    tac[q * 4 + 1] += m * (d1 > 0.f ? d1 : 0.f);
    tac[q * 4 + 2] += m * (d2 > 0.f ? d2 : 0.f);
    tac[q * 4 + 3] += m * (d3 > 0.f ? d3 : 0.f);
  }
}

// ======================= cooperative mega kernel =======================
__global__ __launch_bounds__(256, 4) void mega_kernel(
    const float* __restrict__ h, const int* __restrict__ ei,
    const float* __restrict__ eb1f, const float* __restrict__ nb1f,
    const float* __restrict__ nb2f, const float* __restrict__ ew1,
    const float* __restrict__ ew2, const float* __restrict__ eb2,
    const float* __restrict__ nw1, const float* __restrict__ nw2,
    short* __restrict__ W1t, short* __restrict__ NW1t, short* __restrict__ NW2t,
    float* __restrict__ c0, int* __restrict__ deg, int* __restrict__ colS,
    unsigned short* __restrict__ g, char* __restrict__ g8,
    float* __restrict__ out, int nN, int nE, int degInt4) {
  __shared__ __align__(16) char sm[73728];   // 72KB: P1 = sW(32K)+sO(16K); P2 = sW1(64K)+sT(8K)
  cg::grid_group grid = cg::this_grid();
  const int tid = threadIdx.x;
  const int bid = blockIdx.x;
  const int nBlk = gridDim.x;
  const int lane = tid & 63, wv = tid >> 6;
  const int lr = lane & 15, grp = lane >> 4;

  // ================= P0: prep (weights + WB fold + zero deg) =================
  for (int idx = bid * 256 + tid; idx < 65664 + degInt4; idx += nBlk * 256) {
    if (idx < 16384) {
      int n = idx >> 7, k = idx & 127;
      W1t[idx] = f2bf(ew1[k * 128 + n]);
    } else if (idx < 32768) {
      int o = idx - 16384; int n = o >> 7, k = o & 127;
      NW1t[n * 256 + k] = f2bf(nw1[k * 128 + n]);
    } else if (idx < 49152) {
      int o = idx - 32768; int n = o >> 7, k = o & 127;
      NW2t[o] = f2bf(nw2[k * 128 + n]);
    } else if (idx < 65536) {
      int o = idx - 49152; int ocol = o & 127, kt = o >> 7;
      float s = 0.f;
      for (int m = 0; m < 128; ++m) s += ew2[kt * 128 + m] * nw1[(128 + m) * 128 + ocol];
      NW1t[ocol * 256 + 128 + kt] = f2bf(s);
    } else if (idx < 65664) {
      int o = idx - 65536;
      float s = 0.f;
      for (int m = 0; m < 128; ++m) s += eb2[m] * nw1[(128 + m) * 128 + o];
      c0[o] = s;
    } else {
      ((int4*)deg)[idx - 65664] = (int4){0, 0, 0, 0};
    }
  }
  grid.sync();

  // ================= P1: g tiles (W1 staged once) + scatter =================
  {
    char* sW = sm;
    char* sO = sm + 32768;
    for (int i = tid; i < 2048; i += 256) {
      int n = i >> 4, kB = (i & 15) * 16;
      *(int4*)(sW + swzB(n, kB, 256)) = ((const int4*)W1t)[i];
    }
    __syncthreads();
    const int gTiles = (nN + 63) >> 6;
    for (int t = bid; t < gTiles; t += nBlk) {
      const int nb = t * 64;
      bf16x8 afr[4];
      {
        int row = nb + wv * 16 + lr;
        int nd = (row < nN) ? row : 0;
        const float* hr = h + (long)nd * 128;
#pragma unroll
        for (int kk = 0; kk < 4; ++kk) {
          int k0 = kk * 32 + grp * 8;
          f32x4 a0 = *(const f32x4*)(hr + k0), a1 = *(const f32x4*)(hr + k0 + 4);
          union { bf16x8 v; short s[8]; } u;
          u.s[0] = f2bf(a0.x); u.s[1] = f2bf(a0.y); u.s[2] = f2bf(a0.z); u.s[3] = f2bf(a0.w);
          u.s[4] = f2bf(a1.x); u.s[5] = f2bf(a1.y); u.s[6] = f2bf(a1.z); u.s[7] = f2bf(a1.w);
          afr[kk] = u.v;
        }
      }
      f32x4 acc[8];
#pragma unroll
      for (int j = 0; j < 8; ++j) acc[j] = (f32x4){0.f, 0.f, 0.f, 0.f};
#pragma unroll
      for (int kk = 0; kk < 4; ++kk) {
        int kB = (kk * 32 + grp * 8) * 2;
#pragma unroll
        for (int j = 0; j < 8; ++j) {
          bf16x8 b = *(const bf16x8*)(sW + swzB(j * 16 + lr, kB, 256));
          acc[j] = __builtin_amdgcn_mfma_f32_16x16x32_bf16(afr[kk], b, acc[j], 0, 0, 0);
        }
      }
      __syncthreads();   // prior tile's sO reads complete
#pragma unroll
      for (int j = 0; j < 8; ++j) {
        int col = j * 16 + lr;
#pragma unroll
        for (int r = 0; r < 4; ++r) {
          int row = wv * 16 + grp * 4 + r;
          *(short*)(sO + row * 256 + ((col * 2) ^ ((row & 7) << 4))) = f2bf(acc[j][r]);
        }
      }
      __syncthreads();
#pragma unroll
      for (int i = 0; i < 4; ++i) {
        int c = i * 256 + tid;
        int row = c >> 4;
        int node = nb + row;
        if (node < nN) {
          union { int4 v; unsigned short s[8]; } u;
          u.v = *(const int4*)(sO + row * 256 + (((c & 15) * 16) ^ ((row & 7) << 4)));
          ((int4*)g)[node * 16 + (c & 15)] = u.v;
          float f0 = bf2f(u.s[0]), f1 = bf2f(u.s[1]), f2 = bf2f(u.s[2]), f3 = bf2f(u.s[3]);
          float f4 = bf2f(u.s[4]), f5 = bf2f(u.s[5]), f6 = bf2f(u.s[6]), f7 = bf2f(u.s[7]);
          int w0 = __builtin_amdgcn_cvt_pk_fp8_f32(f0, f1, 0, false);
          w0 = __builtin_amdgcn_cvt_pk_fp8_f32(f2, f3, w0, true);
          int w1 = __builtin_amdgcn_cvt_pk_fp8_f32(f4, f5, 0, false);
          w1 = __builtin_amdgcn_cvt_pk_fp8_f32(f6, f7, w1, true);
          int2 pk; pk.x = w0; pk.y = w1;
          *(int2*)(g8 + (long)node * 128 + (c & 15) * 8) = pk;
        }
      }
    }
    // scatter (fills this block's remaining time in P1)
    const int scatChunks = (nE + 255) >> 8;
    for (int w = bid; w < scatChunks; w += nBlk) {
      int e = w * 256 + tid;
      if (e < nE) {
        int r = ei[e];
        int pos = atomicAdd(&deg[r], 1);
        if (pos < SLOT_CAP) colS[(long)r * SLOT_CAP + pos] = ei[nE + e];
      }
    }
  }
  grid.sync();

  // ================= P2: agg+node tiles (full W1 resident) =================
  {
    char* sW1 = sm;            // 64KB NW1t [128o][256k] swizzled stride 512
    char* sT  = sm + 65536;    // 8KB [32][128] bf16 swizzled
    for (int i = tid; i < 4096; i += 256) {
      int n = i >> 5, kB = (i & 31) * 16;
      *(int4*)(sW1 + swzB(n, kB, 512)) = ((const int4*)NW1t)[i];
    }
    __syncthreads();
    const int aggTiles = (nN + 31) >> 5;
    const int r0 = (wv >> 1) * 16;
    const int cb = (wv & 1) * 64;
    for (int t = bid; t < aggTiles; t += nBlk) {
      const int nb = t * 32;
      // ---- gather -> sT ----
      {
        int gi = tid >> 3;
        int gn = nb + gi;
        bool gok = gn < nN;
        int nd = gok ? gn : 0;
        long rp = (long)nd * SLOT_CAP;
        int dgv = gok ? deg[nd] : 0;
        if (dgv > SLOT_CAP) dgv = SLOT_CAP;
        int d0 = (tid & 7) * 16;
        float gnb[16];
        {
          u16x8 s0 = *(const u16x8*)(g + (long)nd * 128 + d0);
          u16x8 s1 = *(const u16x8*)(g + (long)nd * 128 + d0 + 8);
          f32x4 e0 = *(const f32x4*)(eb1f + d0),     e1 = *(const f32x4*)(eb1f + d0 + 4);
          f32x4 e2 = *(const f32x4*)(eb1f + d0 + 8), e3 = *(const f32x4*)(eb1f + d0 + 12);
#pragma unroll
          for (int j = 0; j < 4; ++j) {
            gnb[j]      = bf2f(s0[j])     + e0[j];
            gnb[4 + j]  = bf2f(s0[4 + j]) + e1[j];
            gnb[8 + j]  = bf2f(s1[j])     + e2[j];
            gnb[12 + j] = bf2f(s1[4 + j]) + e3[j];
          }
        }
        float tac[16];
#pragma unroll
        for (int j = 0; j < 16; ++j) tac[j] = 0.f;
        int cc0 = (0 < dgv) ? colS[rp + 0] : -1;
        int cc1 = (1 < dgv) ? colS[rp + 1] : -1;
        int cc2 = (2 < dgv) ? colS[rp + 2] : -1;
        int cc3 = (3 < dgv) ? colS[rp + 3] : -1;
        for (int i = 0; i < dgv; i += 4) {
          int ii = i + 4;
          int nx0 = (ii + 0 < dgv) ? colS[rp + ii + 0] : -1;
          int nx1 = (ii + 1 < dgv) ? colS[rp + ii + 1] : -1;
          int nx2 = (ii + 2 < dgv) ? colS[rp + ii + 2] : -1;
          int nx3 = (ii + 3 < dgv) ? colS[rp + ii + 3] : -1;
          long r0l = (long)(cc0 < 0 ? 0 : cc0) * 128;
          long r1l = (long)(cc1 < 0 ? 0 : cc1) * 128;
          long r2l = (long)(cc2 < 0 ? 0 : cc2) * 128;
          long r3l = (long)(cc3 < 0 ? 0 : cc3) * 128;
          int4 a0 = *(const int4*)(g8 + r0l + d0);
          int4 a1 = *(const int4*)(g8 + r1l + d0);
          int4 a2 = *(const int4*)(g8 + r2l + d0);
          int4 a3 = *(const int4*)(g8 + r3l + d0);
          float m0 = cc0 < 0 ? 0.f : 1.f, m1 = cc1 < 0 ? 0.f : 1.f;
          float m2 = cc2 < 0 ? 0.f : 1.f, m3 = cc3 < 0 ? 0.f : 1.f;
          acc16fp8(tac, gnb, a0, m0);
          acc16fp8(tac, gnb, a1, m1);
          acc16fp8(tac, gnb, a2, m2);
          acc16fp8(tac, gnb, a3, m3);
          cc0 = nx0; cc1 = nx1; cc2 = nx2; cc3 = nx3;
        }
        union { int4 v; short s[8]; } p0, p1;
#pragma unroll
        for (int j = 0; j < 8; ++j) { p0.s[j] = f2bf(tac[j]); p1.s[j] = f2bf(tac[8 + j]); }
        *(int4*)(sT + swzB(gi, d0 * 2, 256))      = p0.v;
        *(int4*)(sT + swzB(gi, d0 * 2 + 16, 256)) = p1.v;
      }
      // ---- h A-fragments ----
      const int node = nb + r0 + lr;
      const bool ok = node < nN;
      const int ndd = ok ? node : 0;
      bf16x8 afr[8];
      {
        const float* hr = h + (long)ndd * 128;
#pragma unroll
        for (int kk = 0; kk < 4; ++kk) {
          int k0 = kk * 32 + grp * 8;
          f32x4 a0 = *(const f32x4*)(hr + k0), a1 = *(const f32x4*)(hr + k0 + 4);
          union { bf16x8 v; short s[8]; } u;
          u.s[0] = f2bf(a0.x); u.s[1] = f2bf(a0.y); u.s[2] = f2bf(a0.z); u.s[3] = f2bf(a0.w);
          u.s[4] = f2bf(a1.x); u.s[5] = f2bf(a1.y); u.s[6] = f2bf(a1.z); u.s[7] = f2bf(a1.w);
          if (!ok) u.v = (bf16x8)(__bf16)0.f;
          afr[kk] = u.v;
        }
      }
      __syncthreads();   // sT gather complete
#pragma unroll
      for (int kk = 0; kk < 4; ++kk) {
        afr[4 + kk] = *(const bf16x8*)(sT + swzB(r0 + lr, (kk * 32 + grp * 8) * 2, 256));
      }
      // ---- layer 1 (full K=256 from resident sW1) ----
      f32x4 acc[4];
#pragma unroll
      for (int j = 0; j < 4; ++j) acc[j] = (f32x4){0.f, 0.f, 0.f, 0.f};
#pragma unroll
      for (int kk = 0; kk < 4; ++kk) {
        int kB = (kk * 32 + grp * 8) * 2;
#pragma unroll
        for (int j = 0; j < 4; ++j) {
          bf16x8 b = *(const bf16x8*)(sW1 + swzB(cb + j * 16 + lr, kB, 512));
          acc[j] = __builtin_amdgcn_mfma_f32_16x16x32_bf16(afr[kk], b, acc[j], 0, 0, 0);
        }
      }
#pragma unroll
      for (int kk = 0; kk < 4; ++kk) {
        int kB = 256 + (kk * 32 + grp * 8) * 2;
#pragma unroll
        for (int j = 0; j < 4; ++j) {
          bf16x8 b = *(const bf16x8*)(sW1 + swzB(cb + j * 16 + lr, kB, 512));
          acc[j] = __builtin_amdgcn_mfma_f32_16x16x32_bf16(afr[4 + kk], b, acc[j], 0, 0, 0);
        }
      }
      __syncthreads();   // all sT (T) reads done before relu overwrite
      float degs[4];
#pragma unroll
      for (int r = 0; r < 4; ++r) {
        int nn = nb + r0 + grp * 4 + r;
        degs[r] = (float)deg[nn];
      }
#pragma unroll
      for (int j = 0; j < 4; ++j) {
        int col = cb + j * 16 + lr;
        float bv = nb1f[col];
        float c0v = c0[col];
#pragma unroll
        for (int r = 0; r < 4; ++r) {
          int row = r0 + grp * 4 + r;
          float v = acc[j][r] + bv + degs[r] * c0v;
          v = v > 0.f ? v : 0.f;
          *(short*)(sT + swzB(row, col * 2, 256)) = f2bf(v);
        }
      }
      __syncthreads();
      // ---- layer 2 ----
      f32x4 acc2[4];
#pragma unroll
      for (int j = 0; j < 4; ++j) acc2[j] = (f32x4){0.f, 0.f, 0.f, 0.f};
#pragma unroll
      for (int kk = 0; kk < 4; ++kk) {
        int kB = (kk * 32 + grp * 8) * 2;
        bf16x8 a = *(const bf16x8*)(sT + swzB(r0 + lr, kB, 256));
#pragma unroll
        for (int j = 0; j < 4; ++j) {
          bf16x8 b = *(const bf16x8*)(NW2t + (cb + j * 16 + lr) * 128 + kk * 32 + grp * 8);
          acc2[j] = __builtin_amdgcn_mfma_f32_16x16x32_bf16(a, b, acc2[j], 0, 0, 0);
        }
      }
#pragma unroll
      for (int j = 0; j < 4; ++j) {
        int col = cb + j * 16 + lr;
        float bv = nb2f[col];
#pragma unroll
        for (int r = 0; r < 4; ++r) {
          int nn = nb + r0 + grp * 4 + r;
          if (nn < nN) out[(long)nn * 128 + col] = acc2[j][r] + bv;
        }
      }
      __syncthreads();   // sT free for next tile's gather
    }
  }
}

// ======================= R16 fallback kernels =======================
__global__ void prep_all(const float* __restrict__ ew1, const float* __restrict__ ew2,
                         const float* __restrict__ eb2, const float* __restrict__ nw1,
                         const float* __restrict__ nw2, short* __restrict__ W1t,
                         short* __restrict__ NW1t, short* __restrict__ NW2t,
                         float* __restrict__ c0, int* __restrict__ deg, int degInt4) {
  int idx = blockIdx.x * 256 + threadIdx.x;
  if (idx < 16384) {
    int n = idx >> 7, k = idx & 127;
    W1t[idx] = f2bf(ew1[k * 128 + n]);
  } else if (idx < 32768) {
    int o = idx - 16384; int n = o >> 7, k = o & 127;
    NW1t[n * 256 + k] = f2bf(nw1[k * 128 + n]);
  } else if (idx < 49152) {
    int o = idx - 32768; int n = o >> 7, k = o & 127;
    NW2t[o] = f2bf(nw2[k * 128 + n]);
  } else if (idx < 65536) {
    int o = idx - 49152; int ocol = o & 127, kt = o >> 7;
    float s = 0.f;
    for (int m = 0; m < 128; ++m) s += ew2[kt * 128 + m] * nw1[(128 + m) * 128 + ocol];
    NW1t[ocol * 256 + 128 + kt] = f2bf(s);
  } else if (idx < 65664) {
    int o = idx - 65536;
    float s = 0.f;
    for (int m = 0; m < 128; ++m) s += eb2[m] * nw1[(128 + m) * 128 + o];
    c0[o] = s;
  } else if (idx < 65664 + degInt4) {
    ((int4*)deg)[idx - 65664] = (int4){0, 0, 0, 0};
  }
}

__global__ __launch_bounds__(256) void g_kernel(
    const float* __restrict__ h, const short* __restrict__ W1t,
    unsigned short* __restrict__ gOut, char* __restrict__ g8, int nN) {
  __shared__ __align__(16) char sW[32768];
  __shared__ __align__(16) char sO[16384];

  const int tid = threadIdx.x;
  const int lane = tid & 63, wv = tid >> 6;
  const int lr = lane & 15, grp = lane >> 4;
  const int nb = blockIdx.x * 64;

#pragma unroll
  for (int i = 0; i < 8; ++i) {
    int c = i * 256 + tid;
    int n = c >> 4, kB = (c & 15) * 16;
    *(int4*)(sW + swzB(n, kB, 256)) = ((const int4*)W1t)[c];
  }
  bf16x8 afr[4];
  {
    int row = nb + wv * 16 + lr;
    int nd = (row < nN) ? row : 0;
    const float* hr = h + (long)nd * 128;
#pragma unroll
    for (int kk = 0; kk < 4; ++kk) {
      int k0 = kk * 32 + grp * 8;
      f32x4 a0 = *(const f32x4*)(hr + k0), a1 = *(const f32x4*)(hr + k0 + 4);
      union { bf16x8 v; short s[8]; } u;
      u.s[0] = f2bf(a0.x); u.s[1] = f2bf(a0.y); u.s[2] = f2bf(a0.z); u.s[3] = f2bf(a0.w);
      u.s[4] = f2bf(a1.x); u.s[5] = f2bf(a1.y); u.s[6] = f2bf(a1.z); u.s[7] = f2bf(a1.w);
      afr[kk] = u.v;
    }
  }
  __syncthreads();

  f32x4 acc[8];
#pragma unroll
  for (int j = 0; j < 8; ++j) acc[j] = (f32x4){0.f, 0.f, 0.f, 0.f};
#pragma unroll
  for (int kk = 0; kk < 4; ++kk) {
    int kB = (kk * 32 + grp * 8) * 2;
#pragma unroll
    for (int j = 0; j < 8; ++j) {
      bf16x8 b = *(const bf16x8*)(sW + swzB(j * 16 + lr, kB, 256));
      acc[j] = __builtin_amdgcn_mfma_f32_16x16x32_bf16(afr[kk], b, acc[j], 0, 0, 0);
    }
  }
#pragma unroll
  for (int j = 0; j < 8; ++j) {
    int col = j * 16 + lr;
#pragma unroll
    for (int r = 0; r < 4; ++r) {
      int row = wv * 16 + grp * 4 + r;
      *(short*)(sO + row * 256 + ((col * 2) ^ ((row & 7) << 4))) = f2bf(acc[j][r]);
    }
  }
  __syncthreads();
#pragma unroll
  for (int i = 0; i < 4; ++i) {
    int c = i * 256 + tid;
    int row = c >> 4;
    int node = nb + row;
    if (node < nN) {
      union { int4 v; unsigned short s[8]; } u;
      u.v = *(const int4*)(sO + row * 256 + (((c & 15) * 16) ^ ((row & 7) << 4)));
      ((int4*)gOut)[node * 16 + (c & 15)] = u.v;
      float f0 = bf2f(u.s[0]), f1 = bf2f(u.s[1]), f2 = bf2f(u.s[2]), f3 = bf2f(u.s[3]);
      float f4 = bf2f(u.s[4]), f5 = bf2f(u.s[5]), f6 = bf2f(u.s[6]), f7 = bf2f(u.s[7]);
      int w0 = __builtin_amdgcn_cvt_pk_fp8_f32(f0, f1, 0, false);
      w0 = __builtin_amdgcn_cvt_pk_fp8_f32(f2, f3, w0, true);
      int w1 = __builtin_amdgcn_cvt_pk_fp8_f32(f4, f5, 0, false);
      w1 = __builtin_amdgcn_cvt_pk_fp8_f32(f6, f7, w1, true);
      int2 pk; pk.x = w0; pk.y = w1;
      *(int2*)(g8 + (long)node * 128 + (c & 15) * 8) = pk;
    }
  }
}

__global__ __launch_bounds__(256) void scatter_kernel(
    const int* __restrict__ ei, int* __restrict__ deg, int* __restrict__ colS, int nE) {
  int e = blockIdx.x * 256 + threadIdx.x;
  if (e < nE) {
    int r = ei[e];
    int pos = atomicAdd(&deg[r], 1);
    if (pos < SLOT_CAP) colS[(long)r * SLOT_CAP + pos] = ei[nE + e];
  }
}

__global__ __launch_bounds__(256, 4) void agg_node_kernel(
    const float* __restrict__ h, const unsigned short* __restrict__ g,
    const char* __restrict__ g8, const int* __restrict__ deg,
    const int* __restrict__ colS, const float* __restrict__ eb1,
    const float* __restrict__ b1, const float* __restrict__ b2,
    const short* __restrict__ NW1t, const short* __restrict__ NW2t,
    const float* __restrict__ c0, float* __restrict__ out, int nN) {
  __shared__ __align__(16) char sW1[32768];
  __shared__ __align__(16) char sT[8192];

  const int tid = threadIdx.x;
  const int lane = tid & 63, wv = tid >> 6;
  const int lr = lane & 15, grp = lane >> 4;
  const int nb = blockIdx.x * 32;
  const int r0 = (wv >> 1) * 16;
  const int cb = (wv & 1) * 64;

#pragma unroll
  for (int i = 0; i < 8; ++i) {
    int c = i * 256 + tid;
    int n = c >> 4, kB = (c & 15) * 16;
    *(int4*)(sW1 + swzB(n, kB, 256)) = *(const int4*)(NW1t + n * 256 + (c & 15) * 8);
  }
  {
    int gi = tid >> 3;
    int gn = nb + gi;
    bool gok = gn < nN;
    int nd = gok ? gn : 0;
    long rp = (long)nd * SLOT_CAP;
    int dgv = gok ? deg[nd] : 0;
    if (dgv > SLOT_CAP) dgv = SLOT_CAP;
    int d0 = (tid & 7) * 16;

    float gnb[16];
    {
      u16x8 s0 = *(const u16x8*)(g + (long)nd * 128 + d0);
      u16x8 s1 = *(const u16x8*)(g + (long)nd * 128 + d0 + 8);
      f32x4 e0 = *(const f32x4*)(eb1 + d0),     e1 = *(const f32x4*)(eb1 + d0 + 4);
      f32x4 e2 = *(const f32x4*)(eb1 + d0 + 8), e3 = *(const f32x4*)(eb1 + d0 + 12);
#pragma unroll
      for (int j = 0; j < 4; ++j) {
        gnb[j]      = bf2f(s0[j])     + e0[j];
        gnb[4 + j]  = bf2f(s0[4 + j]) + e1[j];
        gnb[8 + j]  = bf2f(s1[j])     + e2[j];
        gnb[12 + j] = bf2f(s1[4 + j]) + e3[j];
      }
    }
    float tac[16];
#pragma unroll
    for (int j = 0; j < 16; ++j) tac[j] = 0.f;

    int cc0 = (0 < dgv) ? colS[rp + 0] : -1;
    int cc1 = (1 < dgv) ? colS[rp + 1] : -1;
    int cc2 = (2 < dgv) ? colS[rp + 2] : -1;
    int cc3 = (3 < dgv) ? colS[rp + 3] : -1;
    for (int i = 0; i < dgv; i += 4) {
      int ii = i + 4;
      int nx0 = (ii + 0 < dgv) ? colS[rp + ii + 0] : -1;
      int nx1 = (ii + 1 < dgv) ? colS[rp + ii + 1] : -1;
      int nx2 = (ii + 2 < dgv) ? colS[rp + ii + 2] : -1;
      int nx3 = (ii + 3 < dgv) ? colS[rp + ii + 3] : -1;
      long r0l = (long)(cc0 < 0 ? 0 : cc0) * 128;
      long r1l = (long)(cc1 < 0 ? 0 : cc1) * 128;
      long r2l = (long)(cc2 < 0 ? 0 : cc2) * 128;
      long r3l = (long)(cc3 < 0 ? 0 : cc3) * 128;
      int4 a0 = *(const int4*)(g8 + r0l + d0);
      int4 a1 = *(const int4*)(g8 + r1l + d0);
      int4 a2 = *(const int4*)(g8 + r2l + d0);
      int4 a3 = *(const int4*)(g8 + r3l + d0);
      float m0 = cc0 < 0 ? 0.f : 1.f, m1 = cc1 < 0 ? 0.f : 1.f;
      float m2 = cc2 < 0 ? 0.f : 1.f, m3 = cc3 < 0 ? 0.f : 1.f;
      acc16fp8(tac, gnb, a0, m0);
      acc16fp8(tac, gnb, a1, m1);
      acc16fp8(tac, gnb, a2, m2);
      acc16fp8(tac, gnb, a3, m3);
      cc0 = nx0; cc1 = nx1; cc2 = nx2; cc3 = nx3;
    }
    union { int4 v; short s[8]; } p0, p1;
#pragma unroll
    for (int j = 0; j < 8; ++j) { p0.s[j] = f2bf(tac[j]); p1.s[j] = f2bf(tac[8 + j]); }
    *(int4*)(sT + swzB(gi, d0 * 2, 256))      = p0.v;
    *(int4*)(sT + swzB(gi, d0 * 2 + 16, 256)) = p1.v;
  }

  const int node = nb + r0 + lr;
  const bool ok = node < nN;
  const int ndd = ok ? node : 0;
  bf16x8 afr[8];
  {
    const float* hr = h + (long)ndd * 128;
#pragma unroll
    for (int kk = 0; kk < 4; ++kk) {
      int k0 = kk * 32 + grp * 8;
      f32x4 a0 = *(const f32x4*)(hr + k0), a1 = *(const f32x4*)(hr + k0 + 4);
      union { bf16x8 v; short s[8]; } u;
      u.s[0] = f2bf(a0.x); u.s[1] = f2bf(a0.y); u.s[2] = f2bf(a0.z); u.s[3] = f2bf(a0.w);
      u.s[4] = f2bf(a1.x); u.s[5] = f2bf(a1.y); u.s[6] = f2bf(a1.z); u.s[7] = f2bf(a1.w);
      if (!ok) u.v = (bf16x8)(__bf16)0.f;
      afr[kk] = u.v;
    }
  }
  __syncthreads();

#pragma unroll
  for (int kk = 0; kk < 4; ++kk) {
    afr[4 + kk] = *(const bf16x8*)(sT + swzB(r0 + lr, (kk * 32 + grp * 8) * 2, 256));
  }

  f32x4 acc[4];
#pragma unroll
  for (int j = 0; j < 4; ++j) acc[j] = (f32x4){0.f, 0.f, 0.f, 0.f};
#pragma unroll
  for (int kk = 0; kk < 4; ++kk) {
    int kB = (kk * 32 + grp * 8) * 2;
#pragma unroll
    for (int j = 0; j < 4; ++j) {
      bf16x8 b = *(const bf16x8*)(sW1 + swzB(cb + j * 16 + lr, kB, 256));
      acc[j] = __builtin_amdgcn_mfma_f32_16x16x32_bf16(afr[kk], b, acc[j], 0, 0, 0);
    }
  }
  __syncthreads();

#pragma unroll
  for (int i = 0; i < 8; ++i) {
    int c = i * 256 + tid;
    int n = c >> 4, kB = (c & 15) * 16;
    *(int4*)(sW1 + swzB(n, kB, 256)) = *(const int4*)(NW1t + n * 256 + 128 + (c & 15) * 8);
  }
  __syncthreads();

#pragma unroll
  for (int kk = 0; kk < 4; ++kk) {
    int kB = (kk * 32 + grp * 8) * 2;
#pragma unroll
    for (int j = 0; j < 4; ++j) {
      bf16x8 b = *(const bf16x8*)(sW1 + swzB(cb + j * 16 + lr, kB, 256));
      acc[j] = __builtin_amdgcn_mfma_f32_16x16x32_bf16(afr[4 + kk], b, acc[j], 0, 0, 0);
    }
  }
  float degs[4];
#pragma unroll
  for (int r = 0; r < 4; ++r) {
    int nn = nb + r0 + grp * 4 + r;
    degs[r] = (float)deg[nn];
  }
#pragma unroll
  for (int j = 0; j < 4; ++j) {
    int col = cb + j * 16 + lr;
    float bv = b1[col];
    float c0v = c0[col];
#pragma unroll
    for (int r = 0; r < 4; ++r) {
      int row = r0 + grp * 4 + r;
      float v = acc[j][r] + bv + degs[r] * c0v;
      v = v > 0.f ? v : 0.f;
      *(short*)(sT + swzB(row, col * 2, 256)) = f2bf(v);
    }
  }
  __syncthreads();

  f32x4 acc2[4];
#pragma unroll
  for (int j = 0; j < 4; ++j) acc2[j] = (f32x4){0.f, 0.f, 0.f, 0.f};
#pragma unroll
  for (int kk = 0; kk < 4; ++kk) {
    int kB = (kk * 32 + grp * 8) * 2;
    bf16x8 a = *(const bf16x8*)(sT + swzB(r0 + lr, kB, 256));
#pragma unroll
    for (int j = 0; j < 4; ++j) {
      bf16x8 b = *(const bf16x8*)(NW2t + (cb + j * 16 + lr) * 128 + kk * 32 + grp * 8);
      acc2[j] = __builtin_amdgcn_mfma_f32_16x16x32_bf16(a, b, acc2[j], 0, 0, 0);
    }
  }
#pragma unroll
  for (int j = 0; j < 4; ++j) {
    int col = cb + j * 16 + lr;
    float bv = b2[col];
#pragma unroll
    for (int r = 0; r < 4; ++r) {
      int nn = nb + r0 + grp * 4 + r;
      if (nn < nN) out[(long)nn * 128 + col] = acc2[j][r] + bv;
    }
  }
}

// ========================================================================
extern "C" void kernel_launch(void* const* d_in, const int* in_sizes, int n_in,
                              void* d_out, int out_size, void* d_ws, size_t ws_size,
                              hipStream_t stream) {
  const float* h   = (const float*)d_in[0];
  const int*   ei  = (const int*)d_in[1];
  const float* ew1 = (const float*)d_in[2];
  const float* eb1 = (const float*)d_in[3];
  const float* ew2 = (const float*)d_in[4];
  const float* eb2 = (const float*)d_in[5];
  const float* nw1 = (const float*)d_in[6];
  const float* nb1 = (const float*)d_in[7];
  const float* nw2 = (const float*)d_in[8];
  const float* nb2 = (const float*)d_in[9];
  float* out = (float*)d_out;

  const int E = in_sizes[1] / 2;            // 600000
  const int N = in_sizes[0] / 128;          // 50000
  const int NP = ((N + 255) / 256) * 256;   // 50176
  int degInt4 = NP / 4;

  // ---- ws layout ----
  char* base = (char*)d_ws;
  short* W1t    = (short*)base;                    // 16384 bf16
  short* NW1t   = W1t + 16384;                     // 32768
  short* NW2t   = NW1t + 32768;                    // 16384
  float* c0     = (float*)(NW2t + 16384);          // 128
  int*   deg    = (int*)(c0 + 128);                // NP
  int*   colS   = deg + NP;                        // NP * SLOT_CAP
  size_t off    = (((size_t)((char*)(colS + (size_t)NP * SLOT_CAP) - base)) + 15) & ~(size_t)15;
  unsigned short* g = (unsigned short*)(base + off);        // NP*128 bf16
  char* g8 = (char*)(g + (size_t)NP * 128);                 // NP*128 fp8
  size_t needed = off + (size_t)NP * 256 + (size_t)NP * 128;

  if (ws_size >= needed) {
    // ---- try cooperative mega kernel (512 blocks = 2/CU at 72KB LDS) ----
    void* args[] = {(void*)&h, (void*)&ei, (void*)&eb1, (void*)&nb1, (void*)&nb2,
                    (void*)&ew1, (void*)&ew2, (void*)&eb2, (void*)&nw1, (void*)&nw2,
                    (void*)&W1t, (void*)&NW1t, (void*)&NW2t, (void*)&c0, (void*)&deg,
                    (void*)&colS, (void*)&g, (void*)&g8, (void*)&out,
                    (void*)&N, (void*)&E, (void*)&degInt4};
    hipError_t err = hipLaunchCooperativeKernel((const void*)mega_kernel,
                                                dim3(512), dim3(256), args, 0, stream);
    if (err == hipSuccess) return;
    (void)hipGetLastError();   // clear error state, fall through

    // ---- R16 4-kernel fallback ----
    int prepBlocks = (65664 + degInt4 + 255) / 256;
    prep_all<<<prepBlocks, 256, 0, stream>>>(ew1, ew2, eb2, nw1, nw2,
                                             W1t, NW1t, NW2t, c0, deg, degInt4);
    g_kernel<<<(N + 63) / 64, 256, 0, stream>>>(h, W1t, g, g8, N);
    scatter_kernel<<<(E + 255) / 256, 256, 0, stream>>>(ei, deg, colS, E);
    agg_node_kernel<<<(N + 31) / 32, 256, 0, stream>>>(h, g, g8, deg, colS, eb1,
                                                       nb1, nb2, NW1t, NW2t, c0, out, N);
  }
}

// Round 18
// 97.401 us; speedup vs baseline: 2.3596x; 2.3596x over previous
//
#include <hip/hip_runtime.h>
#include <hip/hip_bf16.h>

// GraphConv layer, R18 == R16 (best measured: 97.9us). R17's cooperative mega-kernel
// regressed 2.3x (VGPR 64->120 superset allocation, occupancy 22%, spills) -- reverted.
//   g = h@e_w1 (bf16 + fp8 shadow).  T[n] = sum_edges relu(g[n]+eb1 - g8[col]).
//   out = relu(h@A + T@(e_w2@B) + deg*(e_b2@B) + n_b1)@n_w2 + n_b2.
// 4 kernels: prep -> g -> scatter -> agg_node(32 nodes/256thr/40KB).

typedef __attribute__((ext_vector_type(4))) float f32x4;
typedef __attribute__((ext_vector_type(2))) float f32x2;
typedef __attribute__((ext_vector_type(8))) __bf16 bf16x8;
typedef __attribute__((ext_vector_type(4))) short s16x4;
typedef __attribute__((ext_vector_type(8))) unsigned short u16x8;

#define SLOT_CAP 64

__device__ __forceinline__ short f2bf(float f) {
  unsigned x = __float_as_uint(f);
  x = (x + 0x7fffu + ((x >> 16) & 1u)) >> 16;
  return (short)x;
}
__device__ __forceinline__ float bf2f(unsigned short u) {
  return __uint_as_float(((unsigned)u) << 16);
}
// XOR swizzle on byte bits 4..6 within a row (G4 / m214 r268)
__device__ __forceinline__ int swzB(int row, int colByte, int strideB) {
  return row * strideB + (colByte ^ ((row & 7) << 4));
}

// ================= prep_all: weight prep + WB fold + zero deg =================
__global__ void prep_all(const float* __restrict__ ew1, const float* __restrict__ ew2,
                         const float* __restrict__ eb2, const float* __restrict__ nw1,
                         const float* __restrict__ nw2, short* __restrict__ W1t,
                         short* __restrict__ NW1t, short* __restrict__ NW2t,
                         float* __restrict__ c0, int* __restrict__ deg, int degInt4) {
  int idx = blockIdx.x * 256 + threadIdx.x;
  if (idx < 16384) {                        // W1t [128o][128k] <- e_w1
    int n = idx >> 7, k = idx & 127;
    W1t[idx] = f2bf(ew1[k * 128 + n]);
  } else if (idx < 32768) {                 // NW1t [128o][256k], k<128 <- n_w1[:128]
    int o = idx - 16384; int n = o >> 7, k = o & 127;
    NW1t[n * 256 + k] = f2bf(nw1[k * 128 + n]);
  } else if (idx < 49152) {                 // NW2t [128o][128k] <- n_w2
    int o = idx - 32768; int n = o >> 7, k = o & 127;
    NW2t[o] = f2bf(nw2[k * 128 + n]);
  } else if (idx < 65536) {                 // WB[kt][o] = e_w2[kt,:]@n_w1[128:,o] -> k=128+kt
    int o = idx - 49152; int ocol = o & 127, kt = o >> 7;
    float s = 0.f;
    for (int m = 0; m < 128; ++m) s += ew2[kt * 128 + m] * nw1[(128 + m) * 128 + ocol];
    NW1t[ocol * 256 + 128 + kt] = f2bf(s);
  } else if (idx < 65664) {                 // c0[o] = e_b2@n_w1[128:,o]
    int o = idx - 65536;
    float s = 0.f;
    for (int m = 0; m < 128; ++m) s += eb2[m] * nw1[(128 + m) * 128 + o];
    c0[o] = s;
  } else if (idx < 65664 + degInt4) {       // zero deg (int4 stores)
    ((int4*)deg)[idx - 65664] = (int4){0, 0, 0, 0};
  }
}

// ================= g = h @ e_w1 (bf16 out + fp8 shadow) =================
__global__ __launch_bounds__(256) void g_kernel(
    const float* __restrict__ h, const short* __restrict__ W1t,
    unsigned short* __restrict__ gOut, char* __restrict__ g8, int nN) {
  __shared__ __align__(16) char sW[32768];
  __shared__ __align__(16) char sO[16384];

  const int tid = threadIdx.x;
  const int lane = tid & 63, wv = tid >> 6;
  const int lr = lane & 15, grp = lane >> 4;
  const int nb = blockIdx.x * 64;

#pragma unroll
  for (int i = 0; i < 8; ++i) {
    int c = i * 256 + tid;
    int n = c >> 4, kB = (c & 15) * 16;
    *(int4*)(sW + swzB(n, kB, 256)) = ((const int4*)W1t)[c];
  }
  bf16x8 afr[4];
  {
    int row = nb + wv * 16 + lr;
    int nd = (row < nN) ? row : 0;
    const float* hr = h + (long)nd * 128;
#pragma unroll
    for (int kk = 0; kk < 4; ++kk) {
      int k0 = kk * 32 + grp * 8;
      f32x4 a0 = *(const f32x4*)(hr + k0), a1 = *(const f32x4*)(hr + k0 + 4);
      union { bf16x8 v; short s[8]; } u;
      u.s[0] = f2bf(a0.x); u.s[1] = f2bf(a0.y); u.s[2] = f2bf(a0.z); u.s[3] = f2bf(a0.w);
      u.s[4] = f2bf(a1.x); u.s[5] = f2bf(a1.y); u.s[6] = f2bf(a1.z); u.s[7] = f2bf(a1.w);
      afr[kk] = u.v;
    }
  }
  __syncthreads();

  f32x4 acc[8];
#pragma unroll
  for (int j = 0; j < 8; ++j) acc[j] = (f32x4){0.f, 0.f, 0.f, 0.f};
#pragma unroll
  for (int kk = 0; kk < 4; ++kk) {
    int kB = (kk * 32 + grp * 8) * 2;
#pragma unroll
    for (int j = 0; j < 8; ++j) {
      bf16x8 b = *(const bf16x8*)(sW + swzB(j * 16 + lr, kB, 256));
      acc[j] = __builtin_amdgcn_mfma_f32_16x16x32_bf16(afr[kk], b, acc[j], 0, 0, 0);
    }
  }
#pragma unroll
  for (int j = 0; j < 8; ++j) {
    int col = j * 16 + lr;
#pragma unroll
    for (int r = 0; r < 4; ++r) {
      int row = wv * 16 + grp * 4 + r;
      *(short*)(sO + row * 256 + ((col * 2) ^ ((row & 7) << 4))) = f2bf(acc[j][r]);
    }
  }
  __syncthreads();
#pragma unroll
  for (int i = 0; i < 4; ++i) {
    int c = i * 256 + tid;
    int row = c >> 4;
    int node = nb + row;
    if (node < nN) {
      union { int4 v; unsigned short s[8]; } u;
      u.v = *(const int4*)(sO + row * 256 + (((c & 15) * 16) ^ ((row & 7) << 4)));
      ((int4*)gOut)[node * 16 + (c & 15)] = u.v;
      // fp8 shadow: 8 bf16 -> 8 e4m3 bytes (HW cvt; decode side uses matched HW cvt)
      float f0 = bf2f(u.s[0]), f1 = bf2f(u.s[1]), f2 = bf2f(u.s[2]), f3 = bf2f(u.s[3]);
      float f4 = bf2f(u.s[4]), f5 = bf2f(u.s[5]), f6 = bf2f(u.s[6]), f7 = bf2f(u.s[7]);
      int w0 = __builtin_amdgcn_cvt_pk_fp8_f32(f0, f1, 0, false);
      w0 = __builtin_amdgcn_cvt_pk_fp8_f32(f2, f3, w0, true);
      int w1 = __builtin_amdgcn_cvt_pk_fp8_f32(f4, f5, 0, false);
      w1 = __builtin_amdgcn_cvt_pk_fp8_f32(f6, f7, w1, true);
      int2 pk; pk.x = w0; pk.y = w1;
      *(int2*)(g8 + (long)node * 128 + (c & 15) * 8) = pk;
    }
  }
}

// ================= slot scatter (no LDS -> full occupancy) =================
__global__ __launch_bounds__(256) void scatter_kernel(
    const int* __restrict__ ei, int* __restrict__ deg, int* __restrict__ colS, int nE) {
  int e = blockIdx.x * 256 + threadIdx.x;
  if (e < nE) {
    int r = ei[e];
    int pos = atomicAdd(&deg[r], 1);
    if (pos < SLOT_CAP) colS[(long)r * SLOT_CAP + pos] = ei[nE + e];
  }
}

// decode+accumulate one edge's 16 fp8 dims into tac (masked)
__device__ __forceinline__ void acc16fp8(float* tac, const float* gnb, int4 v, float m) {
  int w[4] = {v.x, v.y, v.z, v.w};
#pragma unroll
  for (int q = 0; q < 4; ++q) {
    f32x2 lo = __builtin_amdgcn_cvt_pk_f32_fp8(w[q], false);
    f32x2 hi = __builtin_amdgcn_cvt_pk_f32_fp8(w[q], true);
    float d0 = gnb[q * 4 + 0] - lo.x;
    float d1 = gnb[q * 4 + 1] - lo.y;
    float d2 = gnb[q * 4 + 2] - hi.x;
    float d3 = gnb[q * 4 + 3] - hi.y;
    tac[q * 4 + 0] += m * (d0 > 0.f ? d0 : 0.f);
    tac[q * 4 + 1] += m * (d1 > 0.f ? d1 : 0.f);
    tac[q * 4 + 2] += m * (d2 > 0.f ? d2 : 0.f);
    tac[q * 4 + 3] += m * (d3 > 0.f ? d3 : 0.f);
  }
}

// ===== fused agg+node: fp8 gather -> sT; 32 nodes / 256 threads / 40KB LDS =====
__global__ __launch_bounds__(256, 4) void agg_node_kernel(
    const float* __restrict__ h, const unsigned short* __restrict__ g,
    const char* __restrict__ g8, const int* __restrict__ deg,
    const int* __restrict__ colS, const float* __restrict__ eb1,
    const float* __restrict__ b1, const float* __restrict__ b2,
    const short* __restrict__ NW1t, const short* __restrict__ NW2t,
    const float* __restrict__ c0, float* __restrict__ out, int nN) {
  __shared__ __align__(16) char sW1[32768];   // one K-half of NW1t [128o][128k] swizzled
  __shared__ __align__(16) char sT[8192];     // T (bf16) then relu stage, [32][128] swizzled

  const int tid = threadIdx.x;
  const int lane = tid & 63, wv = tid >> 6;
  const int lr = lane & 15, grp = lane >> 4;
  const int nb = blockIdx.x * 32;
  const int r0 = (wv >> 1) * 16;             // wv in 0..3 -> r0 in {0,16}
  const int cb = (wv & 1) * 64;

  // ---- stage W1 half-1 (k=0..127); completes by first barrier, overlaps gather ----
#pragma unroll
  for (int i = 0; i < 8; ++i) {
    int c = i * 256 + tid;                 // 2048 chunks of 16B
    int n = c >> 4, kB = (c & 15) * 16;
    *(int4*)(sW1 + swzB(n, kB, 256)) = *(const int4*)(NW1t + n * 256 + (c & 15) * 8);
  }

  // ---- gather T: thread owns node nb+(tid>>3), dims (tid&7)*16 .. +16 (fp8 reads) ----
  {
    int gi = tid >> 3;                   // 0..31
    int gn = nb + gi;
    bool gok = gn < nN;
    int nd = gok ? gn : 0;
    long rp = (long)nd * SLOT_CAP;
    int dgv = gok ? deg[nd] : 0;
    if (dgv > SLOT_CAP) dgv = SLOT_CAP;
    int d0 = (tid & 7) * 16;

    float gnb[16];
    {
      u16x8 s0 = *(const u16x8*)(g + (long)nd * 128 + d0);
      u16x8 s1 = *(const u16x8*)(g + (long)nd * 128 + d0 + 8);
      f32x4 e0 = *(const f32x4*)(eb1 + d0),     e1 = *(const f32x4*)(eb1 + d0 + 4);
      f32x4 e2 = *(const f32x4*)(eb1 + d0 + 8), e3 = *(const f32x4*)(eb1 + d0 + 12);
#pragma unroll
      for (int j = 0; j < 4; ++j) {
        gnb[j]      = bf2f(s0[j])     + e0[j];
        gnb[4 + j]  = bf2f(s0[4 + j]) + e1[j];
        gnb[8 + j]  = bf2f(s1[j])     + e2[j];
        gnb[12 + j] = bf2f(s1[4 + j]) + e3[j];
      }
    }
    float tac[16];
#pragma unroll
    for (int j = 0; j < 16; ++j) tac[j] = 0.f;

    int cc0, cc1, cc2, cc3;              // current batch colS (-1 = invalid)
    cc0 = (0 < dgv) ? colS[rp + 0] : -1;
    cc1 = (1 < dgv) ? colS[rp + 1] : -1;
    cc2 = (2 < dgv) ? colS[rp + 2] : -1;
    cc3 = (3 < dgv) ? colS[rp + 3] : -1;
    for (int i = 0; i < dgv; i += 4) {
      int ii = i + 4;
      int nx0 = (ii + 0 < dgv) ? colS[rp + ii + 0] : -1;
      int nx1 = (ii + 1 < dgv) ? colS[rp + ii + 1] : -1;
      int nx2 = (ii + 2 < dgv) ? colS[rp + ii + 2] : -1;
      int nx3 = (ii + 3 < dgv) ? colS[rp + ii + 3] : -1;
      long r0l = (long)(cc0 < 0 ? 0 : cc0) * 128;
      long r1l = (long)(cc1 < 0 ? 0 : cc1) * 128;
      long r2l = (long)(cc2 < 0 ? 0 : cc2) * 128;
      long r3l = (long)(cc3 < 0 ? 0 : cc3) * 128;
      int4 a0 = *(const int4*)(g8 + r0l + d0);
      int4 a1 = *(const int4*)(g8 + r1l + d0);
      int4 a2 = *(const int4*)(g8 + r2l + d0);
      int4 a3 = *(const int4*)(g8 + r3l + d0);
      float m0 = cc0 < 0 ? 0.f : 1.f, m1 = cc1 < 0 ? 0.f : 1.f;
      float m2 = cc2 < 0 ? 0.f : 1.f, m3 = cc3 < 0 ? 0.f : 1.f;
      acc16fp8(tac, gnb, a0, m0);
      acc16fp8(tac, gnb, a1, m1);
      acc16fp8(tac, gnb, a2, m2);
      acc16fp8(tac, gnb, a3, m3);
      cc0 = nx0; cc1 = nx1; cc2 = nx2; cc3 = nx3;
    }
    union { int4 v; short s[8]; } p0, p1;
#pragma unroll
    for (int j = 0; j < 8; ++j) { p0.s[j] = f2bf(tac[j]); p1.s[j] = f2bf(tac[8 + j]); }
    *(int4*)(sT + swzB(gi, d0 * 2, 256))      = p0.v;
    *(int4*)(sT + swzB(gi, d0 * 2 + 16, 256)) = p1.v;
  }

  // ---- h A-fragments direct from global (overlap with barrier wait) ----
  const int node = nb + r0 + lr;
  const bool ok = node < nN;
  const int ndd = ok ? node : 0;
  bf16x8 afr[8];
  {
    const float* hr = h + (long)ndd * 128;
#pragma unroll
    for (int kk = 0; kk < 4; ++kk) {
      int k0 = kk * 32 + grp * 8;
      f32x4 a0 = *(const f32x4*)(hr + k0), a1 = *(const f32x4*)(hr + k0 + 4);
      union { bf16x8 v; short s[8]; } u;
      u.s[0] = f2bf(a0.x); u.s[1] = f2bf(a0.y); u.s[2] = f2bf(a0.z); u.s[3] = f2bf(a0.w);
      u.s[4] = f2bf(a1.x); u.s[5] = f2bf(a1.y); u.s[6] = f2bf(a1.z); u.s[7] = f2bf(a1.w);
      if (!ok) u.v = (bf16x8)(__bf16)0.f;
      afr[kk] = u.v;
    }
  }
  __syncthreads();   // W1 half-1 staged + T written

  // ---- T A-fragments from sT ----
#pragma unroll
  for (int kk = 0; kk < 4; ++kk) {
    afr[4 + kk] = *(const bf16x8*)(sT + swzB(r0 + lr, (kk * 32 + grp * 8) * 2, 256));
  }

  // ---- layer 1 phase A: h x W1[:,0:128], B from sW1 (half-1) ----
  f32x4 acc[4];
#pragma unroll
  for (int j = 0; j < 4; ++j) acc[j] = (f32x4){0.f, 0.f, 0.f, 0.f};
#pragma unroll
  for (int kk = 0; kk < 4; ++kk) {
    int kB = (kk * 32 + grp * 8) * 2;
#pragma unroll
    for (int j = 0; j < 4; ++j) {
      bf16x8 b = *(const bf16x8*)(sW1 + swzB(cb + j * 16 + lr, kB, 256));
      acc[j] = __builtin_amdgcn_mfma_f32_16x16x32_bf16(afr[kk], b, acc[j], 0, 0, 0);
    }
  }
  __syncthreads();   // phase-A B reads + all T reads done

  // ---- restage W1 half-2 (k=128..255) over sW1 ----
#pragma unroll
  for (int i = 0; i < 8; ++i) {
    int c = i * 256 + tid;
    int n = c >> 4, kB = (c & 15) * 16;
    *(int4*)(sW1 + swzB(n, kB, 256)) = *(const int4*)(NW1t + n * 256 + 128 + (c & 15) * 8);
  }
  __syncthreads();   // half-2 staged

  // ---- layer 1 phase B: T x W1[:,128:256] ----
#pragma unroll
  for (int kk = 0; kk < 4; ++kk) {
    int kB = (kk * 32 + grp * 8) * 2;
#pragma unroll
    for (int j = 0; j < 4; ++j) {
      bf16x8 b = *(const bf16x8*)(sW1 + swzB(cb + j * 16 + lr, kB, 256));
      acc[j] = __builtin_amdgcn_mfma_f32_16x16x32_bf16(afr[4 + kk], b, acc[j], 0, 0, 0);
    }
  }
  float degs[4];
#pragma unroll
  for (int r = 0; r < 4; ++r) {
    int nn = nb + r0 + grp * 4 + r;
    degs[r] = (float)deg[nn];            // deg zeroed through NP
  }
#pragma unroll
  for (int j = 0; j < 4; ++j) {
    int col = cb + j * 16 + lr;
    float bv = b1[col];
    float c0v = c0[col];
#pragma unroll
    for (int r = 0; r < 4; ++r) {
      int row = r0 + grp * 4 + r;
      float v = acc[j][r] + bv + degs[r] * c0v;
      v = v > 0.f ? v : 0.f;
      *(short*)(sT + swzB(row, col * 2, 256)) = f2bf(v);
    }
  }
  __syncthreads();

  // ---- layer 2: A from sT, B from global NW2t (L2-resident) ----
  f32x4 acc2[4];
#pragma unroll
  for (int j = 0; j < 4; ++j) acc2[j] = (f32x4){0.f, 0.f, 0.f, 0.f};
#pragma unroll
  for (int kk = 0; kk < 4; ++kk) {
    int kB = (kk * 32 + grp * 8) * 2;
    bf16x8 a = *(const bf16x8*)(sT + swzB(r0 + lr, kB, 256));
#pragma unroll
    for (int j = 0; j < 4; ++j) {
      bf16x8 b = *(const bf16x8*)(NW2t + (cb + j * 16 + lr) * 128 + kk * 32 + grp * 8);
      acc2[j] = __builtin_amdgcn_mfma_f32_16x16x32_bf16(a, b, acc2[j], 0, 0, 0);
    }
  }
#pragma unroll
  for (int j = 0; j < 4; ++j) {
    int col = cb + j * 16 + lr;
    float bv = b2[col];
#pragma unroll
    for (int r = 0; r < 4; ++r) {
      int nn = nb + r0 + grp * 4 + r;
      if (nn < nN) out[(long)nn * 128 + col] = acc2[j][r] + bv;
    }
  }
}

// ========================================================================
// ================= minimal fallback (per-edge atomics, 160KB ws) ========
// ========================================================================
__global__ void prep_kernel_fb(const float* __restrict__ ew1, const float* __restrict__ ew2,
                               const float* __restrict__ nw1, const float* __restrict__ nw2,
                               short* __restrict__ wsS) {
  int idx = blockIdx.x * 256 + threadIdx.x;
  if (idx < 16384) {
    int n = idx >> 7, k = idx & 127;
    wsS[idx] = f2bf(ew1[k * 128 + n]);
  } else if (idx < 32768) {
    int o = idx - 16384; int n = o >> 7, k = o & 127;
    wsS[idx] = f2bf(ew2[k * 128 + n]);
  } else if (idx < 65536) {
    int o = idx - 32768; int n = o >> 8, k = o & 255;
    wsS[idx] = f2bf(nw1[k * 128 + n]);
  } else if (idx < 81920) {
    int o = idx - 65536; int n = o >> 7, k = o & 127;
    wsS[idx] = f2bf(nw2[k * 128 + n]);
  }
}

__global__ __launch_bounds__(512) void edge_kernel_fb(
    const float* __restrict__ h, const int* __restrict__ ei,
    const float* __restrict__ b1, const float* __restrict__ b2,
    const short* __restrict__ W1t, const short* __restrict__ W2t,
    float* __restrict__ agg, int nE) {
  __shared__ __align__(16) char sW1[32768];
  __shared__ __align__(16) char sW2[32768];
  __shared__ __align__(16) char sT[32768];

  const int tid = threadIdx.x;
  const int lane = tid & 63, wv = tid >> 6;
  const int lr = lane & 15, grp = lane >> 4;
  const int eb = blockIdx.x * 128;
  const int* rowI = ei;
  const int* colI = ei + nE;

#pragma unroll
  for (int i = 0; i < 4; ++i) {
    int c = i * 512 + tid;
    int n = c >> 4, kB = (c & 15) * 16;
    *(int4*)(sW1 + swzB(n, kB, 256)) = ((const int4*)W1t)[c];
    *(int4*)(sW2 + swzB(n, kB, 256)) = ((const int4*)W2t)[c];
  }
  bf16x8 afr[4];
  {
    int slot = eb + wv * 16 + lr;
    int r = 0, cc = 0;
    if (slot < nE) { r = rowI[slot]; cc = colI[slot]; }
    const float* hr = h + (long)r * 128;
    const float* hc = h + (long)cc * 128;
#pragma unroll
    for (int kk = 0; kk < 4; ++kk) {
      int k0 = kk * 32 + grp * 8;
      f32x4 a0 = *(const f32x4*)(hr + k0), a1 = *(const f32x4*)(hr + k0 + 4);
      f32x4 c0_ = *(const f32x4*)(hc + k0), c1 = *(const f32x4*)(hc + k0 + 4);
      union { bf16x8 v; short s[8]; } u;
      u.s[0] = f2bf(a0.x - c0_.x); u.s[1] = f2bf(a0.y - c0_.y);
      u.s[2] = f2bf(a0.z - c0_.z); u.s[3] = f2bf(a0.w - c0_.w);
      u.s[4] = f2bf(a1.x - c1.x); u.s[5] = f2bf(a1.y - c1.y);
      u.s[6] = f2bf(a1.z - c1.z); u.s[7] = f2bf(a1.w - c1.w);
      afr[kk] = u.v;
    }
  }
  __syncthreads();

  f32x4 acc[8];
#pragma unroll
  for (int j = 0; j < 8; ++j) acc[j] = (f32x4){0.f, 0.f, 0.f, 0.f};
#pragma unroll
  for (int kk = 0; kk < 4; ++kk) {
    int kB = (kk * 32 + grp * 8) * 2;
#pragma unroll
    for (int j = 0; j < 8; ++j) {
      bf16x8 b = *(const bf16x8*)(sW1 + swzB(j * 16 + lr, kB, 256));
      acc[j] = __builtin_amdgcn_mfma_f32_16x16x32_bf16(afr[kk], b, acc[j], 0, 0, 0);
    }
  }
#pragma unroll
  for (int j = 0; j < 8; ++j) {
    int col = j * 16 + lr;
    float bv = b1[col];
#pragma unroll
    for (int r = 0; r < 4; ++r) {
      int row = wv * 16 + grp * 4 + r;
      float v = acc[j][r] + bv;
      v = v > 0.f ? v : 0.f;
      *(short*)(sT + swzB(row, col * 2, 256)) = f2bf(v);
    }
  }
  __syncthreads();

  f32x4 acc2[8];
#pragma unroll
  for (int j = 0; j < 8; ++j) acc2[j] = (f32x4){0.f, 0.f, 0.f, 0.f};
#pragma unroll
  for (int kk = 0; kk < 4; ++kk) {
    int kB = (kk * 32 + grp * 8) * 2;
    bf16x8 a = *(const bf16x8*)(sT + swzB(wv * 16 + lr, kB, 256));
#pragma unroll
    for (int j = 0; j < 8; ++j) {
      bf16x8 b = *(const bf16x8*)(sW2 + swzB(j * 16 + lr, kB, 256));
      acc2[j] = __builtin_amdgcn_mfma_f32_16x16x32_bf16(a, b, acc2[j], 0, 0, 0);
    }
  }
  int nd[4]; bool okr[4];
#pragma unroll
  for (int r = 0; r < 4; ++r) {
    int e = eb + wv * 16 + grp * 4 + r;
    okr[r] = e < nE;
    nd[r] = okr[r] ? rowI[e] : 0;
  }
#pragma unroll
  for (int j = 0; j < 8; ++j) {
    int col = j * 16 + lr;
    float bv = b2[col];
#pragma unroll
    for (int r = 0; r < 4; ++r) {
      if (okr[r]) atomicAdd(agg + (long)nd[r] * 128 + col, acc2[j][r] + bv);
    }
  }
}

__global__ __launch_bounds__(512) void node_kernel_fb(
    const float* __restrict__ h, const float* agg,
    const float* __restrict__ b1, const float* __restrict__ b2,
    const short* __restrict__ W1t, const short* __restrict__ W2t,
    float* out, int nN) {
  __shared__ __align__(16) char sZ[32768];
  __shared__ __align__(16) char sW1[65536];
  __shared__ __align__(16) char sW2[32768];
  __shared__ __align__(16) char sT[16384];

  const int tid = threadIdx.x;
  const int lane = tid & 63, wv = tid >> 6;
  const int lr = lane & 15, grp = lane >> 4;
  const int nb = blockIdx.x * 64;

#pragma unroll
  for (int i = 0; i < 8; ++i) {
    int c = i * 512 + tid;
    int n = c >> 5, kB = (c & 31) * 16;
    *(int4*)(sW1 + swzB(n, kB, 512)) = ((const int4*)W1t)[c];
  }
#pragma unroll
  for (int i = 0; i < 4; ++i) {
    int c = i * 512 + tid;
    int n = c >> 4, kB = (c & 15) * 16;
    *(int4*)(sW2 + swzB(n, kB, 256)) = ((const int4*)W2t)[c];
  }
  {
    int i = tid >> 3;
    int node = nb + i;
    bool ok = node < nN;
    int nd = ok ? node : 0;
#pragma unroll
    for (int it = 0; it < 8; ++it) {
      int c4 = (tid & 7) + it * 8;
      int col = c4 * 4;
      f32x4 v;
      if (col < 128) v = *(const f32x4*)(h + (long)nd * 128 + col);
      else           v = *(const f32x4*)(agg + (long)nd * 128 + (col - 128));
      if (!ok) v = (f32x4){0.f, 0.f, 0.f, 0.f};
      s16x4 p;
      p.x = f2bf(v.x); p.y = f2bf(v.y); p.z = f2bf(v.z); p.w = f2bf(v.w);
      *(s16x4*)(sZ + swzB(i, col * 2, 512)) = p;
    }
  }
  __syncthreads();

  const int r0 = (wv >> 1) * 16;
  const int cb = (wv & 1) * 64;
  f32x4 acc[4];
#pragma unroll
  for (int j = 0; j < 4; ++j) acc[j] = (f32x4){0.f, 0.f, 0.f, 0.f};
#pragma unroll
  for (int kk = 0; kk < 8; ++kk) {
    int kB = (kk * 32 + grp * 8) * 2;
    bf16x8 a = *(const bf16x8*)(sZ + swzB(r0 + lr, kB, 512));
#pragma unroll
    for (int j = 0; j < 4; ++j) {
      bf16x8 b = *(const bf16x8*)(sW1 + swzB(cb + j * 16 + lr, kB, 512));
      acc[j] = __builtin_amdgcn_mfma_f32_16x16x32_bf16(a, b, acc[j], 0, 0, 0);
    }
  }
#pragma unroll
  for (int j = 0; j < 4; ++j) {
    int col = cb + j * 16 + lr;
    float bv = b1[col];
#pragma unroll
    for (int r = 0; r < 4; ++r) {
      int row = r0 + grp * 4 + r;
      float v = acc[j][r] + bv;
      v = v > 0.f ? v : 0.f;
      *(short*)(sT + swzB(row, col * 2, 256)) = f2bf(v);
    }
  }
  __syncthreads();

  f32x4 acc2[4];
#pragma unroll
  for (int j = 0; j < 4; ++j) acc2[j] = (f32x4){0.f, 0.f, 0.f, 0.f};
#pragma unroll
  for (int kk = 0; kk < 4; ++kk) {
    int kB = (kk * 32 + grp * 8) * 2;
    bf16x8 a = *(const bf16x8*)(sT + swzB(r0 + lr, kB, 256));
#pragma unroll
    for (int j = 0; j < 4; ++j) {
      bf16x8 b = *(const bf16x8*)(sW2 + swzB(cb + j * 16 + lr, kB, 256));
      acc2[j] = __builtin_amdgcn_mfma_f32_16x16x32_bf16(a, b, acc2[j], 0, 0, 0);
    }
  }
#pragma unroll
  for (int j = 0; j < 4; ++j) {
    int col = cb + j * 16 + lr;
    float bv = b2[col];
#pragma unroll
    for (int r = 0; r < 4; ++r) {
      int node = nb + r0 + grp * 4 + r;
      if (node < nN) out[(long)node * 128 + col] = acc2[j][r] + bv;
    }
  }
}

// ========================================================================
extern "C" void kernel_launch(void* const* d_in, const int* in_sizes, int n_in,
                              void* d_out, int out_size, void* d_ws, size_t ws_size,
                              hipStream_t stream) {
  const float* h   = (const float*)d_in[0];
  const int*   ei  = (const int*)d_in[1];
  const float* ew1 = (const float*)d_in[2];
  const float* eb1 = (const float*)d_in[3];
  const float* ew2 = (const float*)d_in[4];
  const float* eb2 = (const float*)d_in[5];
  const float* nw1 = (const float*)d_in[6];
  const float* nb1 = (const float*)d_in[7];
  const float* nw2 = (const float*)d_in[8];
  const float* nb2 = (const float*)d_in[9];
  float* out = (float*)d_out;

  const int E = in_sizes[1] / 2;            // 600000
  const int N = in_sizes[0] / 128;          // 50000
  const int NP = ((N + 255) / 256) * 256;   // 50176
  const int degInt4 = NP / 4;

  // ---- ws layout ----
  char* base = (char*)d_ws;
  short* W1t    = (short*)base;                    // 16384 bf16
  short* NW1t   = W1t + 16384;                     // 32768
  short* NW2t   = NW1t + 32768;                    // 16384
  float* c0     = (float*)(NW2t + 16384);          // 128
  int*   deg    = (int*)(c0 + 128);                // NP
  int*   colS   = deg + NP;                        // NP * SLOT_CAP
  size_t off    = (((size_t)((char*)(colS + (size_t)NP * SLOT_CAP) - base)) + 15) & ~(size_t)15;
  unsigned short* g = (unsigned short*)(base + off);        // NP*128 bf16
  char* g8 = (char*)(g + (size_t)NP * 128);                 // NP*128 fp8
  size_t needed = off + (size_t)NP * 256 + (size_t)NP * 128;

  if (ws_size >= needed) {
    int prepBlocks = (65664 + degInt4 + 255) / 256;
    prep_all<<<prepBlocks, 256, 0, stream>>>(ew1, ew2, eb2, nw1, nw2,
                                             W1t, NW1t, NW2t, c0, deg, degInt4);
    g_kernel<<<(N + 63) / 64, 256, 0, stream>>>(h, W1t, g, g8, N);
    scatter_kernel<<<(E + 255) / 256, 256, 0, stream>>>(ei, deg, colS, E);
    agg_node_kernel<<<(N + 31) / 32, 256, 0, stream>>>(h, g, g8, deg, colS, eb1,
                                                       nb1, nb2, NW1t, NW2t, c0, out, N);
    return;
  }

  // ---- fallback: per-edge atomics (needs only 160KB ws) ----
  short* wsS   = (short*)d_ws;
  short* fW1t  = wsS;
  short* fW2t  = wsS + 16384;
  short* fNW1t = wsS + 32768;
  short* fNW2t = wsS + 65536;
  hipMemsetAsync(d_out, 0, (size_t)out_size * sizeof(float), stream);
  prep_kernel_fb<<<320, 256, 0, stream>>>(ew1, ew2, nw1, nw2, wsS);
  edge_kernel_fb<<<(E + 127) / 128, 512, 0, stream>>>(h, ei, eb1, eb2, fW1t, fW2t, out, E);
  node_kernel_fb<<<(N + 63) / 64, 512, 0, stream>>>(h, out, nb1, nb2, fNW1t, fNW2t, out, N);
}